// Round 7
// baseline (1254.071 us; speedup 1.0000x reference)
//
#include <hip/hip_runtime.h>
#include <math.h>

// Problem dims
#define B_    256
#define P_    196
#define E_    2048
#define H_    2048
#define A_    512
#define EMB_  300
#define VOUT_ 261
#define T_    7

// xcat layout: [ h (2048) | emb (300) | pad(4) | awe (2048) | pad (208) ] K=4608
#define KPAD_   4608
#define EMBOFF_ 2048
#define AWEOFF_ 2352

#define NSTEP_  2880   // combined step GEMM cols: att2 512 | fbeta 2048 | fc 320
#define FCOFF_  2560
#define GSPLIT_ 4      // gates GEMM K-splits (KPAD_/4 = 1152 = 18*64)

typedef __attribute__((ext_vector_type(8))) short          short8_t;
typedef __attribute__((ext_vector_type(8))) unsigned short ushort8_t;
typedef __attribute__((ext_vector_type(4))) float          f32x4;

__device__ __forceinline__ unsigned short f2b(float f) {
    union { float f; unsigned int u; } v; v.f = f;
    unsigned int x = v.u;
    unsigned int r = (x + 0x7fffu + ((x >> 16) & 1u)) >> 16;   // RNE
    return (unsigned short)r;
}
__device__ __forceinline__ float b2f(unsigned short u) {
    union { unsigned int u; float f; } v; v.u = ((unsigned int)u) << 16;
    return v.f;
}
__device__ __forceinline__ ushort8_t pack8(float4 u0, float4 u1) {
    ushort8_t u;
    u[0]=f2b(u0.x); u[1]=f2b(u0.y); u[2]=f2b(u0.z); u[3]=f2b(u0.w);
    u[4]=f2b(u1.x); u[5]=f2b(u1.y); u[6]=f2b(u1.z); u[7]=f2b(u1.w);
    return u;
}

// ---------------------------------------------------------------------------
// Unified MFMA GEMM, BM=256, BN={64,128}, K-step 64, reg-prefetch,
// XOR-swizzled LDS (conflict-free ds_read_b128).
//   SPLITK=1: grid (N/BN, KSPLIT); fp32 partials at Cout + blockIdx.y*256*ldc.
//   SPLITK=0: bf16 C (+bias).
//   XCDSWZ=1: 1D grid of (Mtiles*nbx) blocks; decode so all nbx N-blocks of an
//             M-tile land on one XCD (A-panel L2 reuse).
// ---------------------------------------------------------------------------
template<bool SPLITK, bool OUT16, bool XCDSWZ, int BN>
__global__ __launch_bounds__(256)
void gemm_sk(const unsigned short* __restrict__ Ab, int lda,
             const unsigned short* __restrict__ Bw, int ldb,
             void* __restrict__ Cout, int ldc,
             int Kper, int colbase, const float* __restrict__ bias, int nbx)
{
    constexpr int NB32 = BN / 32;    // B staging row-groups
    constexpr int NF   = BN / 16;    // B fragments per wave
    __shared__ ushort8_t As8[256 * 8];   // 32 KB
    __shared__ ushort8_t Bs8[BN * 8];    //  8/16 KB

    const int tid  = threadIdx.x;
    const int lane = tid & 63;
    const int w    = tid >> 6;

    int nblk, mblk;
    if (XCDSWZ) {
        const int bid  = blockIdx.x;
        const int pair = (bid & 7) * (gridDim.x >> 3) + (bid >> 3);
        nblk = pair % nbx;
        mblk = pair / nbx;
    } else {
        nblk = blockIdx.x;
        mblk = 0;
    }
    const int col0  = colbase + nblk * BN;
    const int kbase = SPLITK ? blockIdx.y * Kper : 0;
    const int mrow0 = XCDSWZ ? mblk * 256 : 0;

    const int rb  = tid >> 3;            // 0..31
    const int seg = tid & 7;
    const int swz = seg ^ (rb & 7);

    const unsigned short* Ap = Ab + (size_t)(mrow0 + rb) * lda + kbase + seg * 8;
    const unsigned short* Bp = Bw + (size_t)(col0 + rb) * ldb + kbase + seg * 8;

    const int lr = lane & 15;
    const int hi = lane >> 4;

    f32x4 acc[4][NF];
    #pragma unroll
    for (int m = 0; m < 4; ++m)
        #pragma unroll
        for (int n = 0; n < NF; ++n)
            acc[m][n] = (f32x4){0.f, 0.f, 0.f, 0.f};

    ushort8_t aR[8], bR[NB32];
    #pragma unroll
    for (int i = 0; i < 8; ++i)
        aR[i] = *(const ushort8_t*)(Ap + (size_t)i * 32 * lda);
    #pragma unroll
    for (int j = 0; j < NB32; ++j)
        bR[j] = *(const ushort8_t*)(Bp + (size_t)j * 32 * ldb);

    for (int k0 = 0; k0 < Kper; k0 += 64) {
        __syncthreads();
        #pragma unroll
        for (int i = 0; i < 8; ++i)
            As8[(rb + i * 32) * 8 + swz] = aR[i];
        #pragma unroll
        for (int j = 0; j < NB32; ++j)
            Bs8[(rb + j * 32) * 8 + swz] = bR[j];
        __syncthreads();
        if (k0 + 64 < Kper) {
            #pragma unroll
            for (int i = 0; i < 8; ++i)
                aR[i] = *(const ushort8_t*)(Ap + (size_t)i * 32 * lda + k0 + 64);
            #pragma unroll
            for (int j = 0; j < NB32; ++j)
                bR[j] = *(const ushort8_t*)(Bp + (size_t)j * 32 * ldb + k0 + 64);
        }
        #pragma unroll
        for (int kc = 0; kc < 2; ++kc) {
            short8_t af[4], bf[NF];
            #pragma unroll
            for (int m = 0; m < 4; ++m) {
                const int row = w * 64 + m * 16 + lr;
                af[m] = *(const short8_t*)&As8[row * 8 + ((kc * 4 + hi) ^ (row & 7))];
            }
            #pragma unroll
            for (int n = 0; n < NF; ++n) {
                const int row = n * 16 + lr;
                bf[n] = *(const short8_t*)&Bs8[row * 8 + ((kc * 4 + hi) ^ (row & 7))];
            }
            #pragma unroll
            for (int m = 0; m < 4; ++m)
                #pragma unroll
                for (int n = 0; n < NF; ++n)
                    acc[m][n] = __builtin_amdgcn_mfma_f32_16x16x32_bf16(
                        af[m], bf[n], acc[m][n], 0, 0, 0);
        }
    }

    // C/D: col = lane&15, row = (lane>>4)*4 + reg
    if (OUT16) {
        unsigned short* C16 = (unsigned short*)Cout;
        #pragma unroll
        for (int m = 0; m < 4; ++m) {
            const int grow0 = mrow0 + w * 64 + m * 16 + hi * 4;
            #pragma unroll
            for (int n = 0; n < NF; ++n) {
                const int gcol = col0 + n * 16 + lr;
                const float bv = bias[gcol];
                #pragma unroll
                for (int r = 0; r < 4; ++r)
                    C16[(size_t)(grow0 + r) * ldc + gcol] = f2b(acc[m][n][r] + bv);
            }
        }
    } else {
        float* Cs = (float*)Cout + (SPLITK ? (size_t)blockIdx.y * 256 * ldc : 0);
        #pragma unroll
        for (int m = 0; m < 4; ++m) {
            const int grow0 = w * 64 + m * 16 + hi * 4;
            #pragma unroll
            for (int n = 0; n < NF; ++n) {
                const int gcol = col0 + n * 16 + lr;
                #pragma unroll
                for (int r = 0; r < 4; ++r)
                    Cs[(size_t)(grow0 + r) * ldc + gcol] = acc[m][n][r];
            }
        }
    }
}

// ---------------------------------------------------------------------------
// Fallback big-M GEMM with fp32 A (only if workspace can't hold enc16)
// ---------------------------------------------------------------------------
__global__ __launch_bounds__(256)
void gemm_mfma_f32(const float* __restrict__ Af, int lda,
                   const unsigned short* __restrict__ Bw, int ldb,
                   unsigned short* __restrict__ Cp, int ldc,
                   const float* __restrict__ bias,
                   int M, int N, int K)
{
    __shared__ __align__(16) unsigned short As[64][40];
    __shared__ __align__(16) unsigned short Bs[128][40];

    const int tid  = threadIdx.x;
    const int lane = tid & 63;
    const int wid  = tid >> 6;
    const int wr   = wid >> 1;
    const int wc   = wid & 1;
    const int row0 = blockIdx.y * 64;
    const int col0 = blockIdx.x * 128;

    const int ar = tid >> 2;
    const int as = (tid & 3) * 8;
    const int br = tid >> 1;
    const int bs = (tid & 1) * 16;

    const int lr = lane & 15;
    const int lk = (lane >> 4) * 8;

    f32x4 acc[2][4];
    #pragma unroll
    for (int m = 0; m < 2; ++m)
        #pragma unroll
        for (int n = 0; n < 4; ++n)
            acc[m][n] = (f32x4){0.f, 0.f, 0.f, 0.f};

    for (int k0 = 0; k0 < K; k0 += 32) {
        ushort8_t aval = {0,0,0,0,0,0,0,0};
        if (row0 + ar < M) {
            const float* p = Af + (size_t)(row0 + ar) * lda + k0 + as;
            aval = pack8(*(const float4*)(p), *(const float4*)(p + 4));
        }
        ushort8_t bv0 = {0,0,0,0,0,0,0,0}, bv1 = {0,0,0,0,0,0,0,0};
        if (col0 + br < N) {
            const unsigned short* p = Bw + (size_t)(col0 + br) * ldb + k0 + bs;
            bv0 = *(const ushort8_t*)(p);
            bv1 = *(const ushort8_t*)(p + 8);
        }
        __syncthreads();
        *(ushort8_t*)&As[ar][as]     = aval;
        *(ushort8_t*)&Bs[br][bs]     = bv0;
        *(ushort8_t*)&Bs[br][bs + 8] = bv1;
        __syncthreads();

        short8_t af[2], bf[4];
        #pragma unroll
        for (int m = 0; m < 2; ++m)
            af[m] = *(const short8_t*)&As[wr * 32 + m * 16 + lr][lk];
        #pragma unroll
        for (int n = 0; n < 4; ++n)
            bf[n] = *(const short8_t*)&Bs[wc * 64 + n * 16 + lr][lk];
        #pragma unroll
        for (int m = 0; m < 2; ++m)
            #pragma unroll
            for (int n = 0; n < 4; ++n)
                acc[m][n] = __builtin_amdgcn_mfma_f32_16x16x32_bf16(
                    af[m], bf[n], acc[m][n], 0, 0, 0);
    }

    #pragma unroll
    for (int m = 0; m < 2; ++m) {
        const int grow0 = row0 + wr * 32 + m * 16 + (lane >> 4) * 4;
        #pragma unroll
        for (int n = 0; n < 4; ++n) {
            const int gcol = col0 + wc * 64 + n * 16 + lr;
            if (gcol >= N) continue;
            const float bv = bias[gcol];
            #pragma unroll
            for (int r = 0; r < 4; ++r) {
                const int grow = grow0 + r;
                if (grow >= M) continue;
                Cp[(size_t)grow * ldc + gcol] = f2b(acc[m][n][r] + bv);
            }
        }
    }
}

// ---------------------------------------------------------------------------
__global__ __launch_bounds__(256)
void cvt_bf16_kernel(const float* __restrict__ in, unsigned short* __restrict__ out,
                     int n8)
{
    const int idx = blockIdx.x * 256 + threadIdx.x;
    if (idx >= n8) return;
    const size_t base = (size_t)idx * 8;
    *(ushort8_t*)(out + base) =
        pack8(*(const float4*)(in + base), *(const float4*)(in + base + 4));
}

// wcat (8192 x 4608) k-order: [W_hh 2048 | W_ih-emb 300 | pad 4 | W_ih-awe 2048 | pad 208]
__global__ __launch_bounds__(256)
void build_wcat_kernel(const float* __restrict__ W_ih, const float* __restrict__ W_hh,
                       unsigned short* __restrict__ wcat)
{
    const int row = blockIdx.x;
    const int LIH = EMB_ + E_;   // 2348
    for (int s = threadIdx.x; s < KPAD_ / 8; s += 256) {
        const int k0 = s * 8;
        ushort8_t u;
        const float* src = nullptr;
        if (k0 + 8 <= H_)                         src = W_hh + (size_t)row * H_ + k0;
        else if (k0 >= H_ && k0 + 8 <= 2344)      src = W_ih + (size_t)row * LIH + (k0 - H_);
        else if (k0 >= AWEOFF_ && k0 + 8 <= 4400) src = W_ih + (size_t)row * LIH + (k0 - 2052);
        if (src) {
            u = pack8(*(const float4*)(src), *(const float4*)(src + 4));
        } else {
            #pragma unroll
            for (int i = 0; i < 8; ++i) {
                const int k = k0 + i;
                float v = 0.f;
                if (k >= H_ && k < 2348)           v = W_ih[(size_t)row * LIH + (k - H_)];
                else if (k >= AWEOFF_ && k < 4400) v = W_ih[(size_t)row * LIH + (k - 2052)];
                u[i] = f2b(v);
            }
        }
        *(ushort8_t*)(wcat + (size_t)row * KPAD_ + k0) = u;
    }
}

// wstep (2880 x 2048) rows: [dec_attW 512 | fbeta_W 2048 | fc_W 261 | 0 pad]
__global__ __launch_bounds__(256)
void build_wstep_kernel(const float* __restrict__ dec_attW,
                        const float* __restrict__ fbeta_W,
                        const float* __restrict__ fc_W,
                        unsigned short* __restrict__ wstep)
{
    const int row = blockIdx.x;
    const int c0  = threadIdx.x * 8;
    const float* src;
    if (row < A_)                   src = dec_attW + (size_t)row * H_ + c0;
    else if (row < A_ + E_)         src = fbeta_W + (size_t)(row - A_) * H_ + c0;
    else if (row < A_ + E_ + VOUT_) src = fc_W + (size_t)(row - A_ - E_) * H_ + c0;
    else                            src = nullptr;
    ushort8_t u = {0,0,0,0,0,0,0,0};
    if (src) u = pack8(*(const float4*)(src), *(const float4*)(src + 4));
    *(ushort8_t*)(wstep + (size_t)row * H_ + c0) = u;
}

// h0 partial reduce (8 splits, 256 x 2048) -> bf16 into xcat h region
__global__ __launch_bounds__(256)
void reduce_h0(const float* __restrict__ parts, const float* __restrict__ bias,
               unsigned short* __restrict__ xcat)
{
    const int i = blockIdx.x * 256 + threadIdx.x;   // 256*2048
    const int row = i >> 11, col = i & (H_ - 1);
    float acc = bias[col];
    #pragma unroll
    for (int s = 0; s < 8; ++s)
        acc += parts[(size_t)s * 256 * H_ + i];
    xcat[(size_t)row * KPAD_ + col] = f2b(acc);
}

// ---------------------------------------------------------------------------
// fused att2-reduce + e + softmax. One block per b. p-row per HALF-wave.
// ---------------------------------------------------------------------------
__global__ __launch_bounds__(256)
void fused_att(const float* __restrict__ parts, const float* __restrict__ dec_attb,
               const unsigned short* __restrict__ att1,
               const float* __restrict__ fw_g, const float* __restrict__ fb,
               float* __restrict__ alpha, float* __restrict__ out_a, int t)
{
    const int b = blockIdx.x;
    const int tid = threadIdx.x;
    const int lane = tid & 63;
    const int wid  = tid >> 6;
    __shared__ float att2s[A_];
    __shared__ float es[P_];
    __shared__ float red[4];

    // phase 1: reduce att2 (8 splits) + bias
    #pragma unroll
    for (int it = 0; it < A_ / 256; ++it) {
        const int c = tid + it * 256;
        float acc = dec_attb[c];
        #pragma unroll
        for (int s = 0; s < 8; ++s)
            acc += parts[((size_t)s * B_ + b) * NSTEP_ + c];
        att2s[c] = acc;
    }
    __syncthreads();

    // phase 2: per-lane fragments: 32-lane group covers A=512 as 32x16
    const int l32  = lane & 31;
    const int slot = wid * 2 + (lane >> 5);   // 0..7
    float a2r[16], fwr[16];
    #pragma unroll
    for (int k = 0; k < 16; ++k) {
        a2r[k] = att2s[l32 * 16 + k];
        fwr[k] = fw_g[l32 * 16 + k];
    }
    const float fbv = fb[0];

    // phase 3: e rows, half-wave per p (8 rows in flight per block)
    for (int p = slot; p < P_; p += 8) {
        const unsigned short* row = att1 + ((size_t)b * P_ + p) * A_ + l32 * 16;
        ushort8_t v0 = *(const ushort8_t*)(row);
        ushort8_t v1 = *(const ushort8_t*)(row + 8);
        float acc = 0.f;
        #pragma unroll
        for (int k = 0; k < 8; ++k) {
            float x = b2f(v0[k]) + a2r[k];
            x = x > 0.f ? x : 0.f;
            acc = fmaf(x, fwr[k], acc);
        }
        #pragma unroll
        for (int k = 0; k < 8; ++k) {
            float x = b2f(v1[k]) + a2r[k + 8];
            x = x > 0.f ? x : 0.f;
            acc = fmaf(x, fwr[k + 8], acc);
        }
        #pragma unroll
        for (int off = 16; off > 0; off >>= 1)
            acc += __shfl_xor(acc, off);
        if (l32 == 0) es[p] = acc + fbv;
    }
    __syncthreads();

    // phase 4: softmax over es[0..195]
    float v = (tid < P_) ? es[tid] : -1e30f;
    float m = v;
    #pragma unroll
    for (int off = 32; off > 0; off >>= 1)
        m = fmaxf(m, __shfl_xor(m, off));
    if (lane == 0) red[wid] = m;
    __syncthreads();
    m = fmaxf(fmaxf(red[0], red[1]), fmaxf(red[2], red[3]));
    __syncthreads();
    float p = (tid < P_) ? expf(v - m) : 0.f;
    float s = p;
    #pragma unroll
    for (int off = 32; off > 0; off >>= 1)
        s += __shfl_xor(s, off);
    if (lane == 0) red[wid] = s;
    __syncthreads();
    s = red[0] + red[1] + red[2] + red[3];
    if (tid < P_) {
        const float a = p / s;
        alpha[b * P_ + tid] = a;
        out_a[((size_t)b * T_ + t) * P_ + tid] = a;
    }
}

// ---------------------------------------------------------------------------
// awe partial: grid (2, B). Block (ph,b) accumulates p in [ph*98, ph*98+98)
// into fp32 awe_part[ph][b][:]. Thread handles 8 consecutive e-dims.
// ---------------------------------------------------------------------------
__global__ __launch_bounds__(256)
void awe_part_kernel(const float* __restrict__ alpha,
                     const float* __restrict__ encf,
                     const unsigned short* __restrict__ enc16, int use16,
                     float* __restrict__ awe_part)
{
    const int ph = blockIdx.x;    // 0..1
    const int b  = blockIdx.y;
    const int tid = threadIdx.x;
    __shared__ float al[98];
    if (tid < 98) al[tid] = alpha[b * P_ + ph * 98 + tid];
    __syncthreads();

    const int e0 = tid * 8;
    float acc[8] = {0.f,0.f,0.f,0.f,0.f,0.f,0.f,0.f};
    if (use16) {
        const unsigned short* ep = enc16 + ((size_t)b * P_ + ph * 98) * E_ + e0;
        int p = 0;
        for (; p + 4 <= 98; p += 4) {
            ushort8_t v0 = *(const ushort8_t*)(ep + (size_t)(p + 0) * E_);
            ushort8_t v1 = *(const ushort8_t*)(ep + (size_t)(p + 1) * E_);
            ushort8_t v2 = *(const ushort8_t*)(ep + (size_t)(p + 2) * E_);
            ushort8_t v3 = *(const ushort8_t*)(ep + (size_t)(p + 3) * E_);
            const float a0 = al[p], a1 = al[p + 1], a2 = al[p + 2], a3 = al[p + 3];
            #pragma unroll
            for (int k = 0; k < 8; ++k) {
                float t0 = fmaf(a0, b2f(v0[k]), acc[k]);
                float t1 = fmaf(a1, b2f(v1[k]), t0);
                float t2 = fmaf(a2, b2f(v2[k]), t1);
                acc[k]   = fmaf(a3, b2f(v3[k]), t2);
            }
        }
        for (; p < 98; ++p) {
            ushort8_t v0 = *(const ushort8_t*)(ep + (size_t)p * E_);
            const float a0 = al[p];
            #pragma unroll
            for (int k = 0; k < 8; ++k)
                acc[k] = fmaf(a0, b2f(v0[k]), acc[k]);
        }
    } else {
        const float* ep = encf + ((size_t)b * P_ + ph * 98) * E_ + e0;
        for (int p = 0; p < 98; ++p) {
            float4 v0 = *(const float4*)(ep + (size_t)p * E_);
            float4 v1 = *(const float4*)(ep + (size_t)p * E_ + 4);
            const float a0 = al[p];
            acc[0] = fmaf(a0, v0.x, acc[0]); acc[1] = fmaf(a0, v0.y, acc[1]);
            acc[2] = fmaf(a0, v0.z, acc[2]); acc[3] = fmaf(a0, v0.w, acc[3]);
            acc[4] = fmaf(a0, v1.x, acc[4]); acc[5] = fmaf(a0, v1.y, acc[5]);
            acc[6] = fmaf(a0, v1.z, acc[6]); acc[7] = fmaf(a0, v1.w, acc[7]);
        }
    }
    float* dst = awe_part + ((size_t)ph * B_ + b) * E_ + e0;
    *(float4*)(dst)     = make_float4(acc[0], acc[1], acc[2], acc[3]);
    *(float4*)(dst + 4) = make_float4(acc[4], acc[5], acc[6], acc[7]);
}

// ---------------------------------------------------------------------------
// finalize: gatelin-reduce + sigmoid, awe = part0+part1, write xcat awe (bf16);
// emb-gather; fc-reduce(t-1). One block per b.
// ---------------------------------------------------------------------------
__global__ __launch_bounds__(256)
void awe_fin_kernel(const float* __restrict__ parts, const float* __restrict__ fbeta_b,
                    const float* __restrict__ awe_part,
                    const int* __restrict__ ann, const float* __restrict__ embW,
                    unsigned short* __restrict__ xcat,
                    const float* __restrict__ fc_b, float* __restrict__ out_y, int t)
{
    const int b = blockIdx.x;
    const int tid = threadIdx.x;
    const int e0 = tid * 8;

    float4 p0a = *(const float4*)(awe_part + (size_t)b * E_ + e0);
    float4 p0b = *(const float4*)(awe_part + (size_t)b * E_ + e0 + 4);
    float4 p1a = *(const float4*)(awe_part + ((size_t)B_ + b) * E_ + e0);
    float4 p1b = *(const float4*)(awe_part + ((size_t)B_ + b) * E_ + e0 + 4);
    float aw[8] = {p0a.x + p1a.x, p0a.y + p1a.y, p0a.z + p1a.z, p0a.w + p1a.w,
                   p0b.x + p1b.x, p0b.y + p1b.y, p0b.z + p1b.z, p0b.w + p1b.w};

    ushort8_t o;
    #pragma unroll
    for (int k = 0; k < 8; ++k) {
        float g = fbeta_b[e0 + k];
        #pragma unroll
        for (int s = 0; s < 8; ++s)
            g += parts[((size_t)s * B_ + b) * NSTEP_ + A_ + e0 + k];
        const float sg = 1.f / (1.f + expf(-g));
        o[k] = f2b(sg * aw[k]);
    }
    *(ushort8_t*)(xcat + (size_t)b * KPAD_ + AWEOFF_ + e0) = o;

    // emb gather for this step
    const int r = ann[b * T_ + t];
    for (int j = tid; j < EMB_; j += 256)
        xcat[(size_t)b * KPAD_ + EMBOFF_ + j] = f2b(embW[(size_t)r * EMB_ + j]);

    // fc reduce for previous step
    if (t > 0) {
        for (int c = tid; c < VOUT_; c += 256) {
            float a = fc_b[c];
            #pragma unroll
            for (int s = 0; s < 8; ++s)
                a += parts[((size_t)s * B_ + b) * NSTEP_ + FCOFF_ + c];
            out_y[((size_t)b * T_ + (t - 1)) * VOUT_ + c] = a;
        }
    }
}

// ---------------------------------------------------------------------------
// fc partial reduce -> out_y[:, tm1, :] (tail step only)
// ---------------------------------------------------------------------------
__global__ __launch_bounds__(256)
void fc_reduce(const float* __restrict__ parts, const float* __restrict__ fc_b,
               float* __restrict__ out_y, int tm1)
{
    const int i = blockIdx.x * 256 + threadIdx.x;
    if (i >= B_ * VOUT_) return;
    const int b = i / VOUT_;
    const int c = i - b * VOUT_;
    float acc = fc_b[c];
    #pragma unroll
    for (int s = 0; s < 8; ++s)
        acc += parts[((size_t)s * B_ + b) * NSTEP_ + FCOFF_ + c];
    out_y[((size_t)b * T_ + tm1) * VOUT_ + c] = acc;
}

// ---------------------------------------------------------------------------
// LSTM cell from gates partials (GSPLIT_ K-splits of 256x8192) + bias
// ---------------------------------------------------------------------------
__global__ __launch_bounds__(256)
void lstm_kernel(const float* __restrict__ parts, const float* __restrict__ bias4h,
                 float* __restrict__ c, unsigned short* __restrict__ xcat)
{
    const int idx = blockIdx.x * 256 + threadIdx.x;  // b*H + j
    const int b = idx >> 11;
    const int j = idx & (H_ - 1);
    const float* p0 = parts + (size_t)b * 4 * H_;
    const size_t S = (size_t)256 * 4 * H_;
    float gi = bias4h[j],          gf = bias4h[H_ + j];
    float gg = bias4h[2 * H_ + j], go = bias4h[3 * H_ + j];
    #pragma unroll
    for (int s = 0; s < GSPLIT_; ++s) {
        const float* p = p0 + s * S;
        gi += p[j]; gf += p[H_ + j]; gg += p[2 * H_ + j]; go += p[3 * H_ + j];
    }
    const float si = 1.f / (1.f + expf(-gi));
    const float sf = 1.f / (1.f + expf(-gf));
    const float so = 1.f / (1.f + expf(-go));
    const float cn = sf * c[idx] + si * tanhf(gg);
    c[idx] = cn;
    xcat[(size_t)b * KPAD_ + j] = f2b(so * tanhf(cn));
}

__global__ __launch_bounds__(256)
void addvec_kernel(const float* __restrict__ a, const float* __restrict__ b,
                   float* __restrict__ o, int n)
{
    const int i = blockIdx.x * 256 + threadIdx.x;
    if (i < n) o[i] = a[i] + b[i];
}

// ---------------------------------------------------------------------------
extern "C" void kernel_launch(void* const* d_in, const int* in_sizes, int n_in,
                              void* d_out, int out_size, void* d_ws, size_t ws_size,
                              hipStream_t stream)
{
    const float* enc      = (const float*)d_in[0];   // (B,P,E)
    const float* enc_out  = (const float*)d_in[1];   // (B,E)
    const int*   ann      = (const int*)  d_in[2];   // (B,T)
    const float* emb_W    = (const float*)d_in[4];   // (VIN,EMB)
    const float* feat_W   = (const float*)d_in[5];   // (H,E)
    const float* feat_b   = (const float*)d_in[6];
    const float* W_ih     = (const float*)d_in[7];   // (4H, EMB+E)
    const float* W_hh     = (const float*)d_in[8];   // (4H, H)
    const float* b_ih     = (const float*)d_in[9];
    const float* b_hh     = (const float*)d_in[10];
    const float* enc_attW = (const float*)d_in[11];  // (A,E)
    const float* enc_attb = (const float*)d_in[12];
    const float* dec_attW = (const float*)d_in[13];  // (A,H)
    const float* dec_attb = (const float*)d_in[14];
    const float* full_attW= (const float*)d_in[15];  // (1,A)
    const float* full_attb= (const float*)d_in[16];
    const float* fbeta_W  = (const float*)d_in[17];  // (E,H)
    const float* fbeta_b  = (const float*)d_in[18];
    const float* fc_W     = (const float*)d_in[19];  // (VOUT,H)
    const float* fc_b     = (const float*)d_in[20];
    (void)in_sizes; (void)n_in; (void)out_size;

    float* out   = (float*)d_out;
    float* out_y = out;                                 // (B,T,VOUT)
    float* out_a = out + (size_t)B_ * T_ * VOUT_;       // (B,T,P)

    // ---- workspace layout
    char* base = (char*)d_ws;
    size_t off = 0;
    auto alloc = [&](size_t bytes) -> char* {
        char* p = base + off;
        off += (bytes + 255) & ~(size_t)255;
        return p;
    };
    unsigned short* att1_16   = (unsigned short*)alloc((size_t)B_ * P_ * A_ * 2);      // 51.4 MB
    unsigned short* wcat16    = (unsigned short*)alloc((size_t)4 * H_ * KPAD_ * 2);    // 75.5 MB
    unsigned short* wstep16   = (unsigned short*)alloc((size_t)NSTEP_ * H_ * 2);       // 11.8 MB
    unsigned short* encattW16 = (unsigned short*)alloc((size_t)A_ * E_ * 2);
    unsigned short* featW16   = (unsigned short*)alloc((size_t)H_ * E_ * 2);
    unsigned short* encout16  = (unsigned short*)alloc((size_t)B_ * E_ * 2);
    unsigned short* xcat16    = (unsigned short*)alloc((size_t)B_ * KPAD_ * 2);        // 2.4 MB
    float* cbuf     = (float*)alloc((size_t)B_ * H_ * 4);
    float* alpha    = (float*)alloc((size_t)B_ * P_ * 4);
    float* bias4h   = (float*)alloc((size_t)4 * H_ * 4);
    float* awe_part = (float*)alloc((size_t)2 * B_ * E_ * 4);                          // 4.2 MB
    // parts sized for max(step GEMM 8x256x2880, gates GEMM 4x256x8192)
    const size_t parts_elems = (size_t)GSPLIT_ * B_ * 4 * H_;   // 8.39M > 5.90M
    float* parts   = (float*)alloc(parts_elems * 4);                                   // 33.6 MB
    const size_t enc_elems = (size_t)B_ * P_ * E_;
    const int use16 = (off + enc_elems * 2 <= ws_size) ? 1 : 0;
    unsigned short* enc16 = use16 ? (unsigned short*)alloc(enc_elems * 2) : nullptr;

    const dim3 blk(256);

    // ---- setup / conversions
    addvec_kernel<<<dim3((4 * H_ + 255) / 256), blk, 0, stream>>>(b_ih, b_hh, bias4h, 4 * H_);
    cvt_bf16_kernel<<<dim3((A_ * E_ / 8 + 255) / 256), blk, 0, stream>>>(enc_attW, encattW16, A_ * E_ / 8);
    cvt_bf16_kernel<<<dim3((H_ * E_ / 8 + 255) / 256), blk, 0, stream>>>(feat_W, featW16, H_ * E_ / 8);
    cvt_bf16_kernel<<<dim3((B_ * E_ / 8 + 255) / 256), blk, 0, stream>>>(enc_out, encout16, B_ * E_ / 8);
    build_wcat_kernel<<<dim3(4 * H_), blk, 0, stream>>>(W_ih, W_hh, wcat16);
    build_wstep_kernel<<<dim3(NSTEP_), blk, 0, stream>>>(dec_attW, fbeta_W, fc_W, wstep16);
    hipMemsetAsync(xcat16, 0, (size_t)B_ * KPAD_ * 2, stream);
    hipMemsetAsync(cbuf, 0, (size_t)B_ * H_ * 4, stream);
    if (use16)
        cvt_bf16_kernel<<<dim3((int)(enc_elems / 8 + 255) / 256), blk, 0, stream>>>(
            enc, enc16, (int)(enc_elems / 8));

    // ---- att1 = enc16 @ enc_att_W^T + b -> bf16 (B*P, A)
    // BN=128: 196 M-tiles x 4 N-blocks, XCD-chunked (784 % 8 == 0)
    if (use16) {
        gemm_sk<false, true, true, 128><<<dim3(196 * 4), blk, 0, stream>>>(
            enc16, E_, encattW16, E_, att1_16, A_, E_, 0, enc_attb, 4);
    } else {
        dim3 g((A_ + 127) / 128, (B_ * P_) / 64);
        gemm_mfma_f32<<<g, blk, 0, stream>>>(enc, E_, encattW16, E_,
            att1_16, A_, enc_attb, B_ * P_, A_, E_);
    }
    // ---- h0 = enc_out @ feat_W^T + b -> bf16 into xcat h region
    gemm_sk<true, false, false, 64><<<dim3(H_ / 64, 8), blk, 0, stream>>>(
        encout16, E_, featW16, E_, parts, H_, E_ / 8, 0, nullptr, 0);
    reduce_h0<<<dim3(B_ * H_ / 256), blk, 0, stream>>>(parts, feat_b, xcat16);

    // ---- decode steps; step-GEMM t yields att2/gatelin for step t, fc for t-1
    for (int t = 0; t <= T_; ++t) {
        if (t < T_)
            gemm_sk<true, false, false, 64><<<dim3(NSTEP_ / 64, 8), blk, 0, stream>>>(
                xcat16, KPAD_, wstep16, H_, parts, NSTEP_, H_ / 8, 0, nullptr, 0);
        else // only fc columns needed
            gemm_sk<true, false, false, 64><<<dim3((NSTEP_ - FCOFF_) / 64, 8), blk, 0, stream>>>(
                xcat16, KPAD_, wstep16, H_, parts, NSTEP_, H_ / 8, FCOFF_, nullptr, 0);
        if (t == T_) {
            fc_reduce<<<dim3((B_ * VOUT_ + 255) / 256), blk, 0, stream>>>(parts, fc_b, out_y, t - 1);
            break;
        }

        fused_att<<<dim3(B_), blk, 0, stream>>>(parts, dec_attb, att1_16,
                                                full_attW, full_attb, alpha, out_a, t);
        awe_part_kernel<<<dim3(2, B_), blk, 0, stream>>>(alpha, enc, enc16, use16, awe_part);
        awe_fin_kernel<<<dim3(B_), blk, 0, stream>>>(parts, fbeta_b, awe_part,
                                                     ann, emb_W, xcat16, fc_b, out_y, t);

        // gates partials: xcat @ wcat^T (K=4608 split 4)
        gemm_sk<true, false, false, 64><<<dim3(4 * H_ / 64, GSPLIT_), blk, 0, stream>>>(
            xcat16, KPAD_, wcat16, KPAD_, parts, 4 * H_, KPAD_ / GSPLIT_, 0, nullptr, 0);
        lstm_kernel<<<dim3(B_ * H_ / 256), blk, 0, stream>>>(parts, bias4h, cbuf, xcat16);
    }
}

// Round 8
// 1197.221 us; speedup vs baseline: 1.0475x; 1.0475x over previous
//
#include <hip/hip_runtime.h>
#include <math.h>

// Problem dims
#define B_    256
#define P_    196
#define E_    2048
#define H_    2048
#define A_    512
#define EMB_  300
#define VOUT_ 261
#define T_    7

// xcat layout: [ h (2048) | emb (300) | pad(4) | awe (2048) | pad (208) ] K=4608
#define KPAD_   4608
#define EMBOFF_ 2048
#define AWEOFF_ 2352

#define NSTEP_  2880   // combined step GEMM cols: att2 512 | fbeta 2048 | fc 320
#define FCOFF_  2560
#define GSPLIT_ 4      // gates GEMM K-splits (KPAD_/4 = 1152 = 18*64)
#define PSPLIT_ 2      // awe p-splits (196 = 2*98)

typedef __attribute__((ext_vector_type(8))) short          short8_t;
typedef __attribute__((ext_vector_type(8))) unsigned short ushort8_t;
typedef __attribute__((ext_vector_type(4))) float          f32x4;

__device__ __forceinline__ unsigned short f2b(float f) {
    union { float f; unsigned int u; } v; v.f = f;
    unsigned int x = v.u;
    unsigned int r = (x + 0x7fffu + ((x >> 16) & 1u)) >> 16;   // RNE
    return (unsigned short)r;
}
__device__ __forceinline__ float b2f(unsigned short u) {
    union { unsigned int u; float f; } v; v.u = ((unsigned int)u) << 16;
    return v.f;
}
__device__ __forceinline__ ushort8_t pack8(float4 u0, float4 u1) {
    ushort8_t u;
    u[0]=f2b(u0.x); u[1]=f2b(u0.y); u[2]=f2b(u0.z); u[3]=f2b(u0.w);
    u[4]=f2b(u1.x); u[5]=f2b(u1.y); u[6]=f2b(u1.z); u[7]=f2b(u1.w);
    return u;
}

// ---------------------------------------------------------------------------
// Unified MFMA GEMM, BM=256, BN=64, K-step 64, reg-prefetch,
// XOR-swizzled LDS (conflict-free ds_read_b128).
//   SPLITK=1: grid (N/64, KSPLIT); fp32 partials at Cout + blockIdx.y*256*ldc.
//   SPLITK=0: bf16 C (+bias).
//   XCDSWZ=1: 1D grid of (Mtiles*nbx) blocks; all nbx N-blocks of an M-tile
//             land on one XCD (A-panel L2 reuse).
// ---------------------------------------------------------------------------
template<bool SPLITK, bool OUT16, bool XCDSWZ>
__global__ __launch_bounds__(256)
void gemm_sk(const unsigned short* __restrict__ Ab, int lda,
             const unsigned short* __restrict__ Bw, int ldb,
             void* __restrict__ Cout, int ldc,
             int Kper, int colbase, const float* __restrict__ bias, int nbx)
{
    __shared__ ushort8_t As8[256 * 8];   // 32 KB
    __shared__ ushort8_t Bs8[64 * 8];    //  8 KB

    const int tid  = threadIdx.x;
    const int lane = tid & 63;
    const int w    = tid >> 6;

    int nblk, mblk;
    if (XCDSWZ) {
        const int bid  = blockIdx.x;
        const int pair = (bid & 7) * (gridDim.x >> 3) + (bid >> 3);
        nblk = pair % nbx;
        mblk = pair / nbx;
    } else {
        nblk = blockIdx.x;
        mblk = 0;
    }
    const int col0  = colbase + nblk * 64;
    const int kbase = SPLITK ? blockIdx.y * Kper : 0;
    const int mrow0 = XCDSWZ ? mblk * 256 : 0;

    const int rb  = tid >> 3;            // 0..31
    const int seg = tid & 7;
    const int swz = seg ^ (rb & 7);

    const unsigned short* Ap = Ab + (size_t)(mrow0 + rb) * lda + kbase + seg * 8;
    const unsigned short* Bp = Bw + (size_t)(col0 + rb) * ldb + kbase + seg * 8;

    const int lr = lane & 15;
    const int hi = lane >> 4;

    f32x4 acc[4][4];
    #pragma unroll
    for (int m = 0; m < 4; ++m)
        #pragma unroll
        for (int n = 0; n < 4; ++n)
            acc[m][n] = (f32x4){0.f, 0.f, 0.f, 0.f};

    ushort8_t aR[8], bR[2];
    #pragma unroll
    for (int i = 0; i < 8; ++i)
        aR[i] = *(const ushort8_t*)(Ap + (size_t)i * 32 * lda);
    bR[0] = *(const ushort8_t*)(Bp);
    bR[1] = *(const ushort8_t*)(Bp + (size_t)32 * ldb);

    for (int k0 = 0; k0 < Kper; k0 += 64) {
        __syncthreads();
        #pragma unroll
        for (int i = 0; i < 8; ++i)
            As8[(rb + i * 32) * 8 + swz] = aR[i];
        Bs8[rb * 8 + swz]        = bR[0];
        Bs8[(rb + 32) * 8 + swz] = bR[1];
        __syncthreads();
        if (k0 + 64 < Kper) {
            #pragma unroll
            for (int i = 0; i < 8; ++i)
                aR[i] = *(const ushort8_t*)(Ap + (size_t)i * 32 * lda + k0 + 64);
            bR[0] = *(const ushort8_t*)(Bp + k0 + 64);
            bR[1] = *(const ushort8_t*)(Bp + (size_t)32 * ldb + k0 + 64);
        }
        #pragma unroll
        for (int kc = 0; kc < 2; ++kc) {
            short8_t af[4], bf[4];
            #pragma unroll
            for (int m = 0; m < 4; ++m) {
                const int row = w * 64 + m * 16 + lr;
                af[m] = *(const short8_t*)&As8[row * 8 + ((kc * 4 + hi) ^ (row & 7))];
            }
            #pragma unroll
            for (int n = 0; n < 4; ++n) {
                const int row = n * 16 + lr;
                bf[n] = *(const short8_t*)&Bs8[row * 8 + ((kc * 4 + hi) ^ (row & 7))];
            }
            #pragma unroll
            for (int m = 0; m < 4; ++m)
                #pragma unroll
                for (int n = 0; n < 4; ++n)
                    acc[m][n] = __builtin_amdgcn_mfma_f32_16x16x32_bf16(
                        af[m], bf[n], acc[m][n], 0, 0, 0);
        }
    }

    // C/D: col = lane&15, row = (lane>>4)*4 + reg
    if (OUT16) {
        unsigned short* C16 = (unsigned short*)Cout;
        #pragma unroll
        for (int m = 0; m < 4; ++m) {
            const int grow0 = mrow0 + w * 64 + m * 16 + hi * 4;
            #pragma unroll
            for (int n = 0; n < 4; ++n) {
                const int gcol = col0 + n * 16 + lr;
                const float bv = bias[gcol];
                #pragma unroll
                for (int r = 0; r < 4; ++r)
                    C16[(size_t)(grow0 + r) * ldc + gcol] = f2b(acc[m][n][r] + bv);
            }
        }
    } else {
        float* Cs = (float*)Cout + (SPLITK ? (size_t)blockIdx.y * 256 * ldc : 0);
        #pragma unroll
        for (int m = 0; m < 4; ++m) {
            const int grow0 = w * 64 + m * 16 + hi * 4;
            #pragma unroll
            for (int n = 0; n < 4; ++n) {
                const int gcol = col0 + n * 16 + lr;
                #pragma unroll
                for (int r = 0; r < 4; ++r)
                    Cs[(size_t)(grow0 + r) * ldc + gcol] = acc[m][n][r];
            }
        }
    }
}

// ---------------------------------------------------------------------------
// Fallback big-M GEMM with fp32 A (only if workspace can't hold enc16)
// ---------------------------------------------------------------------------
__global__ __launch_bounds__(256)
void gemm_mfma_f32(const float* __restrict__ Af, int lda,
                   const unsigned short* __restrict__ Bw, int ldb,
                   unsigned short* __restrict__ Cp, int ldc,
                   const float* __restrict__ bias,
                   int M, int N, int K)
{
    __shared__ __align__(16) unsigned short As[64][40];
    __shared__ __align__(16) unsigned short Bs[128][40];

    const int tid  = threadIdx.x;
    const int lane = tid & 63;
    const int wid  = tid >> 6;
    const int wr   = wid >> 1;
    const int wc   = wid & 1;
    const int row0 = blockIdx.y * 64;
    const int col0 = blockIdx.x * 128;

    const int ar = tid >> 2;
    const int as = (tid & 3) * 8;
    const int br = tid >> 1;
    const int bs = (tid & 1) * 16;

    const int lr = lane & 15;
    const int lk = (lane >> 4) * 8;

    f32x4 acc[2][4];
    #pragma unroll
    for (int m = 0; m < 2; ++m)
        #pragma unroll
        for (int n = 0; n < 4; ++n)
            acc[m][n] = (f32x4){0.f, 0.f, 0.f, 0.f};

    for (int k0 = 0; k0 < K; k0 += 32) {
        ushort8_t aval = {0,0,0,0,0,0,0,0};
        if (row0 + ar < M) {
            const float* p = Af + (size_t)(row0 + ar) * lda + k0 + as;
            aval = pack8(*(const float4*)(p), *(const float4*)(p + 4));
        }
        ushort8_t bv0 = {0,0,0,0,0,0,0,0}, bv1 = {0,0,0,0,0,0,0,0};
        if (col0 + br < N) {
            const unsigned short* p = Bw + (size_t)(col0 + br) * ldb + k0 + bs;
            bv0 = *(const ushort8_t*)(p);
            bv1 = *(const ushort8_t*)(p + 8);
        }
        __syncthreads();
        *(ushort8_t*)&As[ar][as]     = aval;
        *(ushort8_t*)&Bs[br][bs]     = bv0;
        *(ushort8_t*)&Bs[br][bs + 8] = bv1;
        __syncthreads();

        short8_t af[2], bf[4];
        #pragma unroll
        for (int m = 0; m < 2; ++m)
            af[m] = *(const short8_t*)&As[wr * 32 + m * 16 + lr][lk];
        #pragma unroll
        for (int n = 0; n < 4; ++n)
            bf[n] = *(const short8_t*)&Bs[wc * 64 + n * 16 + lr][lk];
        #pragma unroll
        for (int m = 0; m < 2; ++m)
            #pragma unroll
            for (int n = 0; n < 4; ++n)
                acc[m][n] = __builtin_amdgcn_mfma_f32_16x16x32_bf16(
                    af[m], bf[n], acc[m][n], 0, 0, 0);
    }

    #pragma unroll
    for (int m = 0; m < 2; ++m) {
        const int grow0 = row0 + wr * 32 + m * 16 + (lane >> 4) * 4;
        #pragma unroll
        for (int n = 0; n < 4; ++n) {
            const int gcol = col0 + wc * 64 + n * 16 + lr;
            if (gcol >= N) continue;
            const float bv = bias[gcol];
            #pragma unroll
            for (int r = 0; r < 4; ++r) {
                const int grow = grow0 + r;
                if (grow >= M) continue;
                Cp[(size_t)grow * ldc + gcol] = f2b(acc[m][n][r] + bv);
            }
        }
    }
}

// ---------------------------------------------------------------------------
__global__ __launch_bounds__(256)
void cvt_bf16_kernel(const float* __restrict__ in, unsigned short* __restrict__ out,
                     int n8)
{
    const int idx = blockIdx.x * 256 + threadIdx.x;
    if (idx >= n8) return;
    const size_t base = (size_t)idx * 8;
    *(ushort8_t*)(out + base) =
        pack8(*(const float4*)(in + base), *(const float4*)(in + base + 4));
}

// ---------------------------------------------------------------------------
// merged setup: bias add, 3 weight cvts, wstep build, xcat/cbuf zero.
// region-dispatched on blockIdx.x. Total blocks = 32+512+2048+256+2880+576+512
// ---------------------------------------------------------------------------
__global__ __launch_bounds__(256)
void setup_kernel(const float* __restrict__ b_ih, const float* __restrict__ b_hh,
                  float* __restrict__ bias4h,
                  const float* __restrict__ enc_attW, unsigned short* __restrict__ encattW16,
                  const float* __restrict__ feat_W, unsigned short* __restrict__ featW16,
                  const float* __restrict__ enc_out, unsigned short* __restrict__ encout16,
                  const float* __restrict__ dec_attW, const float* __restrict__ fbeta_W,
                  const float* __restrict__ fc_W, unsigned short* __restrict__ wstep,
                  unsigned short* __restrict__ xcat, float* __restrict__ cbuf)
{
    int bid = blockIdx.x;
    const int tid = threadIdx.x;
    if (bid < 32) {                                     // bias4h
        const int i = bid * 256 + tid;
        bias4h[i] = b_ih[i] + b_hh[i];
        return;
    }
    bid -= 32;
    if (bid < 512) {                                    // enc_attW cvt (A*E)
        const size_t base = ((size_t)bid * 256 + tid) * 8;
        *(ushort8_t*)(encattW16 + base) =
            pack8(*(const float4*)(enc_attW + base), *(const float4*)(enc_attW + base + 4));
        return;
    }
    bid -= 512;
    if (bid < 2048) {                                   // feat_W cvt (H*E)
        const size_t base = ((size_t)bid * 256 + tid) * 8;
        *(ushort8_t*)(featW16 + base) =
            pack8(*(const float4*)(feat_W + base), *(const float4*)(feat_W + base + 4));
        return;
    }
    bid -= 2048;
    if (bid < 256) {                                    // enc_out cvt (B*E)
        const size_t base = ((size_t)bid * 256 + tid) * 8;
        *(ushort8_t*)(encout16 + base) =
            pack8(*(const float4*)(enc_out + base), *(const float4*)(enc_out + base + 4));
        return;
    }
    bid -= 256;
    if (bid < NSTEP_) {                                 // wstep row build
        const int row = bid;
        const int c0  = tid * 8;
        const float* src;
        if (row < A_)                   src = dec_attW + (size_t)row * H_ + c0;
        else if (row < A_ + E_)         src = fbeta_W + (size_t)(row - A_) * H_ + c0;
        else if (row < A_ + E_ + VOUT_) src = fc_W + (size_t)(row - A_ - E_) * H_ + c0;
        else                            src = nullptr;
        ushort8_t u = {0,0,0,0,0,0,0,0};
        if (src) u = pack8(*(const float4*)(src), *(const float4*)(src + 4));
        *(ushort8_t*)(wstep + (size_t)row * H_ + c0) = u;
        return;
    }
    bid -= NSTEP_;
    if (bid < 576) {                                    // xcat zero (B*KPAD ushorts)
        const size_t base = ((size_t)bid * 256 + tid) * 8;
        ushort8_t z = {0,0,0,0,0,0,0,0};
        *(ushort8_t*)(xcat + base) = z;
        return;
    }
    bid -= 576;
    {                                                   // cbuf zero (B*H floats), 512 blocks
        const size_t base = ((size_t)bid * 256 + tid) * 4;
        *(float4*)(cbuf + base) = make_float4(0.f, 0.f, 0.f, 0.f);
    }
}

// wcat (8192 x 4608) k-order: [W_hh 2048 | W_ih-emb 300 | pad 4 | W_ih-awe 2048 | pad 208]
__global__ __launch_bounds__(256)
void build_wcat_kernel(const float* __restrict__ W_ih, const float* __restrict__ W_hh,
                       unsigned short* __restrict__ wcat)
{
    const int row = blockIdx.x;
    const int LIH = EMB_ + E_;   // 2348
    for (int s = threadIdx.x; s < KPAD_ / 8; s += 256) {
        const int k0 = s * 8;
        ushort8_t u;
        const float* src = nullptr;
        if (k0 + 8 <= H_)                         src = W_hh + (size_t)row * H_ + k0;
        else if (k0 >= H_ && k0 + 8 <= 2344)      src = W_ih + (size_t)row * LIH + (k0 - H_);
        else if (k0 >= AWEOFF_ && k0 + 8 <= 4400) src = W_ih + (size_t)row * LIH + (k0 - 2052);
        if (src) {
            u = pack8(*(const float4*)(src), *(const float4*)(src + 4));
        } else {
            #pragma unroll
            for (int i = 0; i < 8; ++i) {
                const int k = k0 + i;
                float v = 0.f;
                if (k >= H_ && k < 2348)           v = W_ih[(size_t)row * LIH + (k - H_)];
                else if (k >= AWEOFF_ && k < 4400) v = W_ih[(size_t)row * LIH + (k - 2052)];
                u[i] = f2b(v);
            }
        }
        *(ushort8_t*)(wcat + (size_t)row * KPAD_ + k0) = u;
    }
}

// h0 partial reduce (8 splits, 256 x 2048) -> bf16 into xcat h region
__global__ __launch_bounds__(256)
void reduce_h0(const float* __restrict__ parts, const float* __restrict__ bias,
               unsigned short* __restrict__ xcat)
{
    const int i = blockIdx.x * 256 + threadIdx.x;   // 256*2048
    const int row = i >> 11, col = i & (H_ - 1);
    float acc = bias[col];
    #pragma unroll
    for (int s = 0; s < 8; ++s)
        acc += parts[(size_t)s * 256 * H_ + i];
    xcat[(size_t)row * KPAD_ + col] = f2b(acc);
}

// ---------------------------------------------------------------------------
// merged att2-reduce + e + softmax + awe-partial. grid (PSPLIT, B).
// Both p-split blocks redo the (cheap, 200KB) e+softmax; each streams its own
// 98-row enc chunk. ph==0 writes out_a.
// ---------------------------------------------------------------------------
__global__ __launch_bounds__(256)
void att_awe_kernel(const float* __restrict__ parts, const float* __restrict__ dec_attb,
                    const unsigned short* __restrict__ att1,
                    const float* __restrict__ fw_g, const float* __restrict__ fb,
                    const float* __restrict__ encf, const unsigned short* __restrict__ enc16,
                    int use16,
                    float* __restrict__ awe_part, float* __restrict__ out_a, int t)
{
    const int ph = blockIdx.x;    // 0..PSPLIT-1
    const int b  = blockIdx.y;
    const int tid = threadIdx.x;
    const int lane = tid & 63;
    const int wid  = tid >> 6;
    __shared__ float att2s[A_];
    __shared__ float es[P_];
    __shared__ float red[4];

    // phase 1: reduce att2 (8 splits) + bias
    #pragma unroll
    for (int it = 0; it < A_ / 256; ++it) {
        const int c = tid + it * 256;
        float acc = dec_attb[c];
        #pragma unroll
        for (int s = 0; s < 8; ++s)
            acc += parts[((size_t)s * B_ + b) * NSTEP_ + c];
        att2s[c] = acc;
    }
    __syncthreads();

    // phase 2: per-lane fragments: 32-lane group covers A=512 as 32x16
    const int l32  = lane & 31;
    const int slot = wid * 2 + (lane >> 5);   // 0..7
    float a2r[16], fwr[16];
    #pragma unroll
    for (int k = 0; k < 16; ++k) {
        a2r[k] = att2s[l32 * 16 + k];
        fwr[k] = fw_g[l32 * 16 + k];
    }
    const float fbv = fb[0];

    // phase 3: e rows, half-wave per p
    for (int p = slot; p < P_; p += 8) {
        const unsigned short* row = att1 + ((size_t)b * P_ + p) * A_ + l32 * 16;
        ushort8_t v0 = *(const ushort8_t*)(row);
        ushort8_t v1 = *(const ushort8_t*)(row + 8);
        float acc = 0.f;
        #pragma unroll
        for (int k = 0; k < 8; ++k) {
            float x = b2f(v0[k]) + a2r[k];
            x = x > 0.f ? x : 0.f;
            acc = fmaf(x, fwr[k], acc);
        }
        #pragma unroll
        for (int k = 0; k < 8; ++k) {
            float x = b2f(v1[k]) + a2r[k + 8];
            x = x > 0.f ? x : 0.f;
            acc = fmaf(x, fwr[k + 8], acc);
        }
        #pragma unroll
        for (int off = 16; off > 0; off >>= 1)
            acc += __shfl_xor(acc, off);
        if (l32 == 0) es[p] = acc + fbv;
    }
    __syncthreads();

    // phase 4: softmax over es[0..195]; es overwritten with alpha
    float v = (tid < P_) ? es[tid] : -1e30f;
    float m = v;
    #pragma unroll
    for (int off = 32; off > 0; off >>= 1)
        m = fmaxf(m, __shfl_xor(m, off));
    if (lane == 0) red[wid] = m;
    __syncthreads();
    m = fmaxf(fmaxf(red[0], red[1]), fmaxf(red[2], red[3]));
    __syncthreads();
    float p = (tid < P_) ? expf(v - m) : 0.f;
    float s = p;
    #pragma unroll
    for (int off = 32; off > 0; off >>= 1)
        s += __shfl_xor(s, off);
    if (lane == 0) red[wid] = s;
    __syncthreads();
    s = red[0] + red[1] + red[2] + red[3];
    float alv = p / s;
    if (tid < P_) {
        if (ph == 0)
            out_a[((size_t)b * T_ + t) * P_ + tid] = alv;
    }
    __syncthreads();                  // es reads done (phase-3 consumers past)
    if (tid < P_) es[tid] = alv;      // es now holds alpha
    __syncthreads();

    // phase 5: stream enc chunk rows [ph*98, ph*98+98)
    const int e0 = tid * 8;
    const int prow0 = ph * 98;
    float acc[8] = {0.f,0.f,0.f,0.f,0.f,0.f,0.f,0.f};
    if (use16) {
        const unsigned short* ep = enc16 + ((size_t)b * P_ + prow0) * E_ + e0;
        int pp = 0;
        for (; pp + 4 <= 98; pp += 4) {
            ushort8_t v0 = *(const ushort8_t*)(ep + (size_t)(pp + 0) * E_);
            ushort8_t v1 = *(const ushort8_t*)(ep + (size_t)(pp + 1) * E_);
            ushort8_t v2 = *(const ushort8_t*)(ep + (size_t)(pp + 2) * E_);
            ushort8_t v3 = *(const ushort8_t*)(ep + (size_t)(pp + 3) * E_);
            const float a0 = es[prow0 + pp],     a1 = es[prow0 + pp + 1];
            const float a2 = es[prow0 + pp + 2], a3 = es[prow0 + pp + 3];
            #pragma unroll
            for (int k = 0; k < 8; ++k) {
                float t0 = fmaf(a0, b2f(v0[k]), acc[k]);
                float t1 = fmaf(a1, b2f(v1[k]), t0);
                float t2 = fmaf(a2, b2f(v2[k]), t1);
                acc[k]   = fmaf(a3, b2f(v3[k]), t2);
            }
        }
        for (; pp < 98; ++pp) {
            ushort8_t v0 = *(const ushort8_t*)(ep + (size_t)pp * E_);
            const float a0 = es[prow0 + pp];
            #pragma unroll
            for (int k = 0; k < 8; ++k)
                acc[k] = fmaf(a0, b2f(v0[k]), acc[k]);
        }
    } else {
        const float* ep = encf + ((size_t)b * P_ + prow0) * E_ + e0;
        for (int pp = 0; pp < 98; ++pp) {
            float4 v0 = *(const float4*)(ep + (size_t)pp * E_);
            float4 v1 = *(const float4*)(ep + (size_t)pp * E_ + 4);
            const float a0 = es[prow0 + pp];
            acc[0] = fmaf(a0, v0.x, acc[0]); acc[1] = fmaf(a0, v0.y, acc[1]);
            acc[2] = fmaf(a0, v0.z, acc[2]); acc[3] = fmaf(a0, v0.w, acc[3]);
            acc[4] = fmaf(a0, v1.x, acc[4]); acc[5] = fmaf(a0, v1.y, acc[5]);
            acc[6] = fmaf(a0, v1.z, acc[6]); acc[7] = fmaf(a0, v1.w, acc[7]);
        }
    }
    float* dst = awe_part + ((size_t)ph * B_ + b) * E_ + e0;
    *(float4*)(dst)     = make_float4(acc[0], acc[1], acc[2], acc[3]);
    *(float4*)(dst + 4) = make_float4(acc[4], acc[5], acc[6], acc[7]);
}

// ---------------------------------------------------------------------------
// finalize: gatelin-reduce + sigmoid, awe = sum(parts), write xcat awe (bf16);
// emb-gather; fc-reduce(t-1). One block per b.
// ---------------------------------------------------------------------------
__global__ __launch_bounds__(256)
void awe_fin_kernel(const float* __restrict__ parts, const float* __restrict__ fbeta_b,
                    const float* __restrict__ awe_part,
                    const int* __restrict__ ann, const float* __restrict__ embW,
                    unsigned short* __restrict__ xcat,
                    const float* __restrict__ fc_b, float* __restrict__ out_y, int t)
{
    const int b = blockIdx.x;
    const int tid = threadIdx.x;
    const int e0 = tid * 8;

    float aw[8] = {0.f,0.f,0.f,0.f,0.f,0.f,0.f,0.f};
    #pragma unroll
    for (int ph = 0; ph < PSPLIT_; ++ph) {
        float4 pa = *(const float4*)(awe_part + ((size_t)ph * B_ + b) * E_ + e0);
        float4 pb = *(const float4*)(awe_part + ((size_t)ph * B_ + b) * E_ + e0 + 4);
        aw[0] += pa.x; aw[1] += pa.y; aw[2] += pa.z; aw[3] += pa.w;
        aw[4] += pb.x; aw[5] += pb.y; aw[6] += pb.z; aw[7] += pb.w;
    }

    ushort8_t o;
    #pragma unroll
    for (int k = 0; k < 8; ++k) {
        float g = fbeta_b[e0 + k];
        #pragma unroll
        for (int s = 0; s < 8; ++s)
            g += parts[((size_t)s * B_ + b) * NSTEP_ + A_ + e0 + k];
        const float sg = 1.f / (1.f + expf(-g));
        o[k] = f2b(sg * aw[k]);
    }
    *(ushort8_t*)(xcat + (size_t)b * KPAD_ + AWEOFF_ + e0) = o;

    // emb gather for this step
    const int r = ann[b * T_ + t];
    for (int j = tid; j < EMB_; j += 256)
        xcat[(size_t)b * KPAD_ + EMBOFF_ + j] = f2b(embW[(size_t)r * EMB_ + j]);

    // fc reduce for previous step
    if (t > 0) {
        for (int c = tid; c < VOUT_; c += 256) {
            float a = fc_b[c];
            #pragma unroll
            for (int s = 0; s < 8; ++s)
                a += parts[((size_t)s * B_ + b) * NSTEP_ + FCOFF_ + c];
            out_y[((size_t)b * T_ + (t - 1)) * VOUT_ + c] = a;
        }
    }
}

// ---------------------------------------------------------------------------
// fc partial reduce -> out_y[:, tm1, :] (tail step only)
// ---------------------------------------------------------------------------
__global__ __launch_bounds__(256)
void fc_reduce(const float* __restrict__ parts, const float* __restrict__ fc_b,
               float* __restrict__ out_y, int tm1)
{
    const int i = blockIdx.x * 256 + threadIdx.x;
    if (i >= B_ * VOUT_) return;
    const int b = i / VOUT_;
    const int c = i - b * VOUT_;
    float acc = fc_b[c];
    #pragma unroll
    for (int s = 0; s < 8; ++s)
        acc += parts[((size_t)s * B_ + b) * NSTEP_ + FCOFF_ + c];
    out_y[((size_t)b * T_ + tm1) * VOUT_ + c] = acc;
}

// ---------------------------------------------------------------------------
// LSTM cell from gates partials (GSPLIT_ K-splits of 256x8192) + bias
// ---------------------------------------------------------------------------
__global__ __launch_bounds__(256)
void lstm_kernel(const float* __restrict__ parts, const float* __restrict__ bias4h,
                 float* __restrict__ c, unsigned short* __restrict__ xcat)
{
    const int idx = blockIdx.x * 256 + threadIdx.x;  // b*H + j
    const int b = idx >> 11;
    const int j = idx & (H_ - 1);
    const float* p0 = parts + (size_t)b * 4 * H_;
    const size_t S = (size_t)256 * 4 * H_;
    float gi = bias4h[j],          gf = bias4h[H_ + j];
    float gg = bias4h[2 * H_ + j], go = bias4h[3 * H_ + j];
    #pragma unroll
    for (int s = 0; s < GSPLIT_; ++s) {
        const float* p = p0 + s * S;
        gi += p[j]; gf += p[H_ + j]; gg += p[2 * H_ + j]; go += p[3 * H_ + j];
    }
    const float si = 1.f / (1.f + expf(-gi));
    const float sf = 1.f / (1.f + expf(-gf));
    const float so = 1.f / (1.f + expf(-go));
    const float cn = sf * c[idx] + si * tanhf(gg);
    c[idx] = cn;
    xcat[(size_t)b * KPAD_ + j] = f2b(so * tanhf(cn));
}

// ---------------------------------------------------------------------------
extern "C" void kernel_launch(void* const* d_in, const int* in_sizes, int n_in,
                              void* d_out, int out_size, void* d_ws, size_t ws_size,
                              hipStream_t stream)
{
    const float* enc      = (const float*)d_in[0];   // (B,P,E)
    const float* enc_out  = (const float*)d_in[1];   // (B,E)
    const int*   ann      = (const int*)  d_in[2];   // (B,T)
    const float* emb_W    = (const float*)d_in[4];   // (VIN,EMB)
    const float* feat_W   = (const float*)d_in[5];   // (H,E)
    const float* feat_b   = (const float*)d_in[6];
    const float* W_ih     = (const float*)d_in[7];   // (4H, EMB+E)
    const float* W_hh     = (const float*)d_in[8];   // (4H, H)
    const float* b_ih     = (const float*)d_in[9];
    const float* b_hh     = (const float*)d_in[10];
    const float* enc_attW = (const float*)d_in[11];  // (A,E)
    const float* enc_attb = (const float*)d_in[12];
    const float* dec_attW = (const float*)d_in[13];  // (A,H)
    const float* dec_attb = (const float*)d_in[14];
    const float* full_attW= (const float*)d_in[15];  // (1,A)
    const float* full_attb= (const float*)d_in[16];
    const float* fbeta_W  = (const float*)d_in[17];  // (E,H)
    const float* fbeta_b  = (const float*)d_in[18];
    const float* fc_W     = (const float*)d_in[19];  // (VOUT,H)
    const float* fc_b     = (const float*)d_in[20];
    (void)in_sizes; (void)n_in; (void)out_size;

    float* out   = (float*)d_out;
    float* out_y = out;                                 // (B,T,VOUT)
    float* out_a = out + (size_t)B_ * T_ * VOUT_;       // (B,T,P)

    // ---- workspace layout
    char* base = (char*)d_ws;
    size_t off = 0;
    auto alloc = [&](size_t bytes) -> char* {
        char* p = base + off;
        off += (bytes + 255) & ~(size_t)255;
        return p;
    };
    unsigned short* att1_16   = (unsigned short*)alloc((size_t)B_ * P_ * A_ * 2);      // 51.4 MB
    unsigned short* wcat16    = (unsigned short*)alloc((size_t)4 * H_ * KPAD_ * 2);    // 75.5 MB
    unsigned short* wstep16   = (unsigned short*)alloc((size_t)NSTEP_ * H_ * 2);       // 11.8 MB
    unsigned short* encattW16 = (unsigned short*)alloc((size_t)A_ * E_ * 2);
    unsigned short* featW16   = (unsigned short*)alloc((size_t)H_ * E_ * 2);
    unsigned short* encout16  = (unsigned short*)alloc((size_t)B_ * E_ * 2);
    unsigned short* xcat16    = (unsigned short*)alloc((size_t)B_ * KPAD_ * 2);        // 2.4 MB
    float* cbuf     = (float*)alloc((size_t)B_ * H_ * 4);
    float* bias4h   = (float*)alloc((size_t)4 * H_ * 4);
    float* awe_part = (float*)alloc((size_t)PSPLIT_ * B_ * E_ * 4);                    // 4.2 MB
    // parts sized for max(step GEMM 8x256x2880, gates GEMM 4x256x8192)
    const size_t parts_elems = (size_t)GSPLIT_ * B_ * 4 * H_;   // 8.39M > 5.90M
    float* parts   = (float*)alloc(parts_elems * 4);                                   // 33.6 MB
    const size_t enc_elems = (size_t)B_ * P_ * E_;
    const int use16 = (off + enc_elems * 2 <= ws_size) ? 1 : 0;
    unsigned short* enc16 = use16 ? (unsigned short*)alloc(enc_elems * 2) : nullptr;

    const dim3 blk(256);

    // ---- merged setup (bias add, weight cvts, wstep build, zeroing)
    setup_kernel<<<dim3(32 + 512 + 2048 + 256 + NSTEP_ + 576 + 512), blk, 0, stream>>>(
        b_ih, b_hh, bias4h, enc_attW, encattW16, feat_W, featW16,
        enc_out, encout16, dec_attW, fbeta_W, fc_W, wstep16, xcat16, cbuf);
    build_wcat_kernel<<<dim3(4 * H_), blk, 0, stream>>>(W_ih, W_hh, wcat16);
    if (use16)
        cvt_bf16_kernel<<<dim3((int)(enc_elems / 8 + 255) / 256), blk, 0, stream>>>(
            enc, enc16, (int)(enc_elems / 8));

    // ---- att1 = enc16 @ enc_att_W^T + b -> bf16 (B*P, A)
    // BN=64: 196 M-tiles x 8 N-blocks, XCD-chunked (1568 % 8 == 0)
    if (use16) {
        gemm_sk<false, true, true><<<dim3(196 * 8), blk, 0, stream>>>(
            enc16, E_, encattW16, E_, att1_16, A_, E_, 0, enc_attb, 8);
    } else {
        dim3 g((A_ + 127) / 128, (B_ * P_) / 64);
        gemm_mfma_f32<<<g, blk, 0, stream>>>(enc, E_, encattW16, E_,
            att1_16, A_, enc_attb, B_ * P_, A_, E_);
    }
    // ---- h0 = enc_out @ feat_W^T + b -> bf16 into xcat h region
    gemm_sk<true, false, false><<<dim3(H_ / 64, 8), blk, 0, stream>>>(
        encout16, E_, featW16, E_, parts, H_, E_ / 8, 0, nullptr, 0);
    reduce_h0<<<dim3(B_ * H_ / 256), blk, 0, stream>>>(parts, feat_b, xcat16);

    // ---- decode steps; step-GEMM t yields att2/gatelin for step t, fc for t-1
    for (int t = 0; t <= T_; ++t) {
        if (t < T_)
            gemm_sk<true, false, false><<<dim3(NSTEP_ / 64, 8), blk, 0, stream>>>(
                xcat16, KPAD_, wstep16, H_, parts, NSTEP_, H_ / 8, 0, nullptr, 0);
        else // only fc columns needed
            gemm_sk<true, false, false><<<dim3((NSTEP_ - FCOFF_) / 64, 8), blk, 0, stream>>>(
                xcat16, KPAD_, wstep16, H_, parts, NSTEP_, H_ / 8, FCOFF_, nullptr, 0);
        if (t == T_) {
            fc_reduce<<<dim3((B_ * VOUT_ + 255) / 256), blk, 0, stream>>>(parts, fc_b, out_y, t - 1);
            break;
        }

        att_awe_kernel<<<dim3(PSPLIT_, B_), blk, 0, stream>>>(
            parts, dec_attb, att1_16, full_attW, full_attb,
            enc, enc16, use16, awe_part, out_a, t);
        awe_fin_kernel<<<dim3(B_), blk, 0, stream>>>(parts, fbeta_b, awe_part,
                                                     ann, emb_W, xcat16, fc_b, out_y, t);

        // gates partials: xcat @ wcat^T (K=4608 split 4)
        gemm_sk<true, false, false><<<dim3(4 * H_ / 64, GSPLIT_), blk, 0, stream>>>(
            xcat16, KPAD_, wcat16, KPAD_, parts, 4 * H_, KPAD_ / GSPLIT_, 0, nullptr, 0);
        lstm_kernel<<<dim3(B_ * H_ / 256), blk, 0, stream>>>(parts, bias4h, cbuf, xcat16);
    }
}